// Round 2
// baseline (608.760 us; speedup 1.0000x reference)
//
#include <hip/hip_runtime.h>
#include <math.h>

// Problem constants
#define Bq 2
#define Nn 20000
#define Ee 20000
#define Aa 8
#define Hh 256
#define TEe 32
constexpr int BE   = Bq * Ee;   // 40000 edges total
constexpr int BN   = Bq * Nn;   // 40000 nodes total
constexpr int KENC = Hh + TEe;  // 288
constexpr int KUPD = 2 * Hh;    // 512
constexpr int EPB  = 16;        // edges per block
constexpr int NPB  = 16;        // nodes per block
constexpr int SLCAP = 1024;     // staged CSR list capacity per node-block

__device__ __forceinline__ float gelu_f(float x) {
    return 0.5f * x * (1.f + erff(x * 0.70710678118654752440f));
}

__device__ __forceinline__ float wred(float v) {
    v += __shfl_xor(v, 1, 64);
    v += __shfl_xor(v, 2, 64);
    v += __shfl_xor(v, 4, 64);
    v += __shfl_xor(v, 8, 64);
    v += __shfl_xor(v, 16, 64);
    v += __shfl_xor(v, 32, 64);
    return v;
}

// mask dtype sniffing: flag bit1 => float32 mask, bit0 => uint8 mask, none => int32
__device__ __forceinline__ float mask_at(const void* mp, int flag, int i) {
    if (flag & 2) return ((const float*)mp)[i];
    if (flag & 1) return ((const unsigned char*)mp)[i] ? 1.f : 0.f;
    return ((const int*)mp)[i] ? 1.f : 0.f;
}

__global__ void k_zero(float4* p, int n4) {
    int i = blockIdx.x * blockDim.x + threadIdx.x;
    int stride = gridDim.x * blockDim.x;
    float4 z; z.x = 0.f; z.y = 0.f; z.z = 0.f; z.w = 0.f;
    for (; i < n4; i += stride) p[i] = z;
}

__global__ void k_detect(const unsigned int* mw, int n, int* flag) {
    int found = 0;
    for (int i = blockIdx.x * blockDim.x + threadIdx.x; i < n;
         i += gridDim.x * blockDim.x) {
        unsigned int w = mw[i];
        if (w == 0x3F800000u) found |= 2;
        else if (w > 1u) found |= 1;
    }
    __shared__ int sf;
    if (threadIdx.x == 0) sf = 0;
    __syncthreads();
    if (found) atomicOr(&sf, found);
    __syncthreads();
    if (threadIdx.x == 0 && sf) atomicOr(flag, sf);
}

// count masked incidences per node
__global__ void k_count(const int* __restrict__ members, const void* __restrict__ maskp,
                        const int* __restrict__ flagp, int* __restrict__ deg) {
    int flag = flagp[0];
    for (int i = blockIdx.x * blockDim.x + threadIdx.x; i < BE * Aa;
         i += gridDim.x * blockDim.x) {
        if (mask_at(maskp, flag, i) != 0.f) {
            int ge = i >> 3;
            int b = ge / Ee;
            int idx = min(max(members[i], 0), Nn - 1);
            atomicAdd(&deg[b * Nn + idx], 1);
        }
    }
}

// exclusive prefix scan of deg[BN] -> offs[BN+1], also init cur = offs
__global__ __launch_bounds__(1024) void k_scan(const int* __restrict__ deg,
                                               int* __restrict__ offs,
                                               int* __restrict__ cur) {
    __shared__ int part[1024];
    const int T = 1024;
    const int C = (BN + T - 1) / T;   // 40
    int t = threadIdx.x;
    int base = t * C;
    int s = 0;
    for (int i = 0; i < C; i++) {
        int j = base + i;
        if (j < BN) s += deg[j];
    }
    part[t] = s;
    __syncthreads();
    for (int d = 1; d < T; d <<= 1) {
        int v = (t >= d) ? part[t - d] : 0;
        __syncthreads();
        part[t] += v;
        __syncthreads();
    }
    int run = (t > 0) ? part[t - 1] : 0;
    for (int i = 0; i < C; i++) {
        int j = base + i;
        if (j < BN) {
            offs[j] = run;
            cur[j] = run;
            run += deg[j];
        }
    }
    if (t == T - 1) offs[BN] = part[T - 1];
}

// fill CSR lists: list[pos] = global edge index
__global__ void k_fill(const int* __restrict__ members, const void* __restrict__ maskp,
                       const int* __restrict__ flagp, int* __restrict__ cur,
                       int* __restrict__ list) {
    int flag = flagp[0];
    for (int i = blockIdx.x * blockDim.x + threadIdx.x; i < BE * Aa;
         i += gridDim.x * blockDim.x) {
        if (mask_at(maskp, flag, i) != 0.f) {
            int ge = i >> 3;
            int b = ge / Ee;
            int idx = min(max(members[i], 0), Nn - 1);
            int pos = atomicAdd(&cur[b * Nn + idx], 1);
            list[pos] = ge;
        }
    }
}

// Edge phase: pool members -> concat type emb -> @W_enc + b -> gelu -> LN -> write ef
__global__ __launch_bounds__(256) void k_edge(
    const float* __restrict__ nf, const int* __restrict__ members,
    const int* __restrict__ types, const void* __restrict__ maskp,
    const float* __restrict__ ett, const float* __restrict__ Wenc,
    const float* __restrict__ benc, const float* __restrict__ genc,
    const float* __restrict__ beenc, const int* __restrict__ flagp,
    float* __restrict__ ef) {
    __shared__ float s_in[EPB][KENC];      // 18 KB
    __shared__ int   s_idx[EPB][Aa];
    __shared__ float s_m[EPB][Aa];
    __shared__ float s_cnt[EPB];
    __shared__ float s_stats[EPB][2];

    const int tid = threadIdx.x;
    const int e0  = blockIdx.x * EPB;
    const int flag = flagp[0];

    if (tid < EPB * Aa) {
        int e = tid >> 3, a = tid & 7;
        int ge = e0 + e;
        int idx = members[ge * Aa + a];
        idx = min(max(idx, 0), Nn - 1);
        s_idx[e][a] = idx;
        s_m[e][a] = mask_at(maskp, flag, ge * Aa + a);
    }
    __syncthreads();
    if (tid < EPB) {
        float c = 0.f;
        #pragma unroll
        for (int a = 0; a < Aa; a++) c += s_m[tid][a];
        s_cnt[tid] = fmaxf(c, 1.f);
    }
    __syncthreads();

    for (int e = 0; e < EPB; e++) {
        int ge = e0 + e;
        int b = ge / Ee;
        const float* nfb = nf + (size_t)b * Nn * Hh;
        float acc = 0.f;
        #pragma unroll
        for (int a = 0; a < Aa; a++) {
            float m = s_m[e][a];
            if (m != 0.f) acc += m * nfb[(size_t)s_idx[e][a] * Hh + tid];
        }
        s_in[e][tid] = acc / s_cnt[e];
    }
    if (tid < TEe) {
        for (int e = 0; e < EPB; e++) {
            int t = types[e0 + e];
            s_in[e][Hh + tid] = ett[t * TEe + tid];
        }
    }
    __syncthreads();

    float acc[EPB];
    {
        float bb = benc[tid];
        #pragma unroll
        for (int e = 0; e < EPB; e++) acc[e] = bb;
    }
    for (int k = 0; k < KENC; k += 4) {
        float w0 = Wenc[(k + 0) * Hh + tid];
        float w1 = Wenc[(k + 1) * Hh + tid];
        float w2 = Wenc[(k + 2) * Hh + tid];
        float w3 = Wenc[(k + 3) * Hh + tid];
        #pragma unroll
        for (int e = 0; e < EPB; e++) {
            float4 iv = *(const float4*)&s_in[e][k];
            acc[e] = fmaf(iv.x, w0, acc[e]);
            acc[e] = fmaf(iv.y, w1, acc[e]);
            acc[e] = fmaf(iv.z, w2, acc[e]);
            acc[e] = fmaf(iv.w, w3, acc[e]);
        }
    }
    __syncthreads();

    #pragma unroll
    for (int e = 0; e < EPB; e++) {
        acc[e] = gelu_f(acc[e]);
        s_in[e][tid] = acc[e];
    }
    __syncthreads();

    int lane = tid & 63, wid = tid >> 6;
    for (int e = wid; e < EPB; e += 4) {
        float4 v = *(const float4*)&s_in[e][lane * 4];
        float s  = v.x + v.y + v.z + v.w;
        float s2 = v.x * v.x + v.y * v.y + v.z * v.z + v.w * v.w;
        s = wred(s); s2 = wred(s2);
        if (lane == 0) {
            float mu = s * (1.f / Hh);
            s_stats[e][0] = mu;
            s_stats[e][1] = rsqrtf(s2 * (1.f / Hh) - mu * mu + 1e-5f);
        }
    }
    __syncthreads();

    float gam = genc[tid], bet = beenc[tid];
    #pragma unroll
    for (int e = 0; e < EPB; e++) {
        float v = (acc[e] - s_stats[e][0]) * s_stats[e][1] * gam + bet;
        ef[(size_t)(e0 + e) * Hh + tid] = v;
    }
}

// Node phase: pooled update via CSR gather, then GEMM2 + gelu + LN
__global__ __launch_bounds__(256) void k_node(
    const float* __restrict__ nf, const float* __restrict__ ef,
    const int* __restrict__ deg, const int* __restrict__ offs,
    const int* __restrict__ list, const float* __restrict__ Wupd,
    const float* __restrict__ bupd, const float* __restrict__ gupd,
    const float* __restrict__ beupd, float* __restrict__ out) {
    __shared__ float s_in[NPB][KUPD];   // 32 KB
    __shared__ float s_stats[NPB][2];
    __shared__ int   s_list[SLCAP];     // 4 KB
    const int tid = threadIdx.x;
    const int n0  = blockIdx.x * NPB;

    // stage the contiguous CSR segment for this block's nodes
    const int segbase = offs[n0];
    const int segtot  = offs[n0 + NPB] - segbase;
    if (segtot <= SLCAP) {
        for (int j = tid; j < segtot; j += 256) s_list[j] = list[segbase + j];
    }
    __syncthreads();

    for (int i = 0; i < NPB; i++) {
        int gn = n0 + i;
        int o0 = offs[gn] - segbase;
        int d  = deg[gn];
        float acc = 0.f;
        if (segtot <= SLCAP) {
            for (int j = 0; j < d; j++) {
                int ge = s_list[o0 + j];
                acc += ef[(size_t)ge * Hh + tid];
            }
        } else {
            for (int j = 0; j < d; j++) {
                int ge = list[segbase + o0 + j];
                acc += ef[(size_t)ge * Hh + tid];
            }
        }
        float c = fmaxf((float)d, 1.f);
        s_in[i][Hh + tid] = acc / c;
        s_in[i][tid] = nf[(size_t)gn * Hh + tid];
    }
    __syncthreads();

    float acc[NPB];
    {
        float bb = bupd[tid];
        #pragma unroll
        for (int i = 0; i < NPB; i++) acc[i] = bb;
    }
    for (int k = 0; k < KUPD; k += 4) {
        float w0 = Wupd[(k + 0) * Hh + tid];
        float w1 = Wupd[(k + 1) * Hh + tid];
        float w2 = Wupd[(k + 2) * Hh + tid];
        float w3 = Wupd[(k + 3) * Hh + tid];
        #pragma unroll
        for (int i = 0; i < NPB; i++) {
            float4 iv = *(const float4*)&s_in[i][k];
            acc[i] = fmaf(iv.x, w0, acc[i]);
            acc[i] = fmaf(iv.y, w1, acc[i]);
            acc[i] = fmaf(iv.z, w2, acc[i]);
            acc[i] = fmaf(iv.w, w3, acc[i]);
        }
    }
    __syncthreads();

    #pragma unroll
    for (int i = 0; i < NPB; i++) {
        acc[i] = gelu_f(acc[i]);
        s_in[i][tid] = acc[i];
    }
    __syncthreads();

    int lane = tid & 63, wid = tid >> 6;
    for (int i = wid; i < NPB; i += 4) {
        float4 v = *(const float4*)&s_in[i][lane * 4];
        float s  = v.x + v.y + v.z + v.w;
        float s2 = v.x * v.x + v.y * v.y + v.z * v.z + v.w * v.w;
        s = wred(s); s2 = wred(s2);
        if (lane == 0) {
            float mu = s * (1.f / Hh);
            s_stats[i][0] = mu;
            s_stats[i][1] = rsqrtf(s2 * (1.f / Hh) - mu * mu + 1e-5f);
        }
    }
    __syncthreads();

    float gam = gupd[tid], bet = beupd[tid];
    for (int i = 0; i < NPB; i++) {
        int gn = n0 + i;
        out[(size_t)gn * Hh + tid] =
            (acc[i] - s_stats[i][0]) * s_stats[i][1] * gam + bet;
    }
}

extern "C" void kernel_launch(void* const* d_in, const int* in_sizes, int n_in,
                              void* d_out, int out_size, void* d_ws, size_t ws_size,
                              hipStream_t stream) {
    const float* nf    = (const float*)d_in[0];
    const int* members = (const int*)d_in[1];
    const int* types   = (const int*)d_in[2];
    const void* maskp  = d_in[3];
    const float* ett   = (const float*)d_in[4];
    const float* Wenc  = (const float*)d_in[5];
    const float* benc  = (const float*)d_in[6];
    const float* genc  = (const float*)d_in[7];
    const float* beenc = (const float*)d_in[8];
    const float* Wupd  = (const float*)d_in[9];
    const float* bupd  = (const float*)d_in[10];
    const float* gupd  = (const float*)d_in[11];
    const float* beupd = (const float*)d_in[12];
    float* out = (float*)d_out;

    // workspace layout (ints)
    int* ip    = (int*)d_ws;
    int* flag  = ip;                        // 64-int pad
    int* deg   = ip + 64;                   // BN
    int* offs  = deg + BN;                  // BN+1 (padded to BN+16)
    int* cur   = offs + BN + 16;            // BN
    int* list  = cur + BN;                  // BE*Aa
    float* ef  = (float*)(list + BE * Aa);  // BE*Hh floats (16B-aligned)

    // zero flag + deg  (64 + BN ints = 10016 float4s)
    int n4 = (64 + BN) / 4;
    hipLaunchKernelGGL(k_zero, dim3(64), dim3(256), 0, stream, (float4*)ip, n4);
    hipLaunchKernelGGL(k_detect, dim3(512), dim3(256), 0, stream,
                       (const unsigned int*)maskp, BE * Aa / 4, flag);
    hipLaunchKernelGGL(k_count, dim3(640), dim3(256), 0, stream,
                       members, maskp, flag, deg);
    hipLaunchKernelGGL(k_scan, dim3(1), dim3(1024), 0, stream, deg, offs, cur);
    hipLaunchKernelGGL(k_fill, dim3(640), dim3(256), 0, stream,
                       members, maskp, flag, cur, list);
    hipLaunchKernelGGL(k_edge, dim3(BE / EPB), dim3(256), 0, stream,
                       nf, members, types, maskp, ett, Wenc, benc, genc, beenc,
                       flag, ef);
    hipLaunchKernelGGL(k_node, dim3(BN / NPB), dim3(256), 0, stream,
                       nf, ef, deg, offs, list, Wupd, bupd, gupd, beupd, out);
}